// Round 2
// baseline (110.586 us; speedup 1.0000x reference)
//
#include <hip/hip_runtime.h>
#include <math.h>

// GaussianMixture log-likelihood: ll[n] = logsumexp_m( wlog[m] - dx^T G_m dx )
// arg(n,m) = c0 + c1*x0^2 + c2*x0 + c3*x1^2 + c4*x1 + c5*x0*x1  (log2-scaled)
// R8: software-pipelined chunk loop. R7 post-mortem: VGPR=48 proves compiler
// rematerialized a[32] (eval ran twice); VALUBusy 71% with 8 waves resident
// shows phase-bunching stalls (all waves hit trans pipe together, then VALU).
// Fix: CH=8 ping-pong buffers; loop body interleaves eval+tree of chunk k
// (full-rate VALU) with exp-phase of chunk k-1 (trans) so each wave always
// carries mixed-pipe work. a[8]x2 = 32 VGPR stays live -> no remat.
// Max tree stays COMPLETE over every element (R5 NaN lesson).
// readfirstlane on wave id keeps coefficient loads scalar (R3 lesson).

#if __has_builtin(__builtin_amdgcn_exp2f)
#define EXP2(x) __builtin_amdgcn_exp2f(x)
#else
#define EXP2(x) exp2f(x)
#endif

typedef float v2f __attribute__((ext_vector_type(2)));

#if __has_builtin(__builtin_elementwise_max)
#define PKMAX(a, b) __builtin_elementwise_max(a, b)
#else
static __device__ inline v2f PKMAX(v2f a, v2f b) {
  v2f r; r.x = fmaxf(a.x, b.x); r.y = fmaxf(a.y, b.y); return r;
}
#endif

#define SPLIT 8
#define CH 8     // pipeline chunk (fast path)
#define CHG 16   // general-path chunk (unchanged from R7)

__global__ __launch_bounds__(256) void prep_kernel(
    const float* __restrict__ mu,
    const float* __restrict__ A,
    const float* __restrict__ w,
    float* __restrict__ C,   // [6][M] planes + header {flag, cb1, cb3, cb5}
    int M) {
  __shared__ float red[256];
  __shared__ int uni[256];
  const int t = threadIdx.x;

  float mx = -INFINITY;
  for (int m = t; m < M; m += 256) mx = fmaxf(mx, w[m]);
  red[t] = mx; __syncthreads();
  for (int s = 128; s > 0; s >>= 1) {
    if (t < s) red[t] = fmaxf(red[t], red[t + s]);
    __syncthreads();
  }
  const float wmax = red[0]; __syncthreads();

  float sum = 0.f;
  for (int m = t; m < M; m += 256) sum += expf(w[m] - wmax);
  red[t] = sum; __syncthreads();
  for (int s = 128; s > 0; s >>= 1) {
    if (t < s) red[t] += red[t + s];
    __syncthreads();
  }
  const float logZ = wmax + logf(red[0]);

  const float r00 = A[0], r01 = A[1], r10 = A[2], r11 = A[3];
  const float rg00 = 0.5f * (r00 * r00 + r01 * r01);
  const float rg01 = 0.5f * (r00 * r10 + r01 * r11);
  const float rg11 = 0.5f * (r10 * r10 + r11 * r11);

  const float LOG2E = 1.44269504088896340736f;
  int myuni = 1;
  for (int m = t; m < M; m += 256) {
    const float a00 = A[m * 4 + 0], a01 = A[m * 4 + 1];
    const float a10 = A[m * 4 + 2], a11 = A[m * 4 + 3];
    const float g00 = 0.5f * (a00 * a00 + a01 * a01);
    const float g01 = 0.5f * (a00 * a10 + a01 * a11);
    const float g11 = 0.5f * (a10 * a10 + a11 * a11);
    const float g01s = 2.0f * g01;
    const float det = g00 * g11 - g01 * g01;
    const float wlog = (w[m] - logZ) + 0.5f * logf(det);
    const float mu0 = mu[m * 2 + 0], mu1 = mu[m * 2 + 1];
    const float c0 = wlog - (g00 * mu0 * mu0 + g01s * mu0 * mu1 + g11 * mu1 * mu1);
    const float c2 = 2.0f * g00 * mu0 + g01s * mu1;
    const float c4 = 2.0f * g11 * mu1 + g01s * mu0;
    C[0 * M + m] = LOG2E * c0;
    C[1 * M + m] = LOG2E * -g00;
    C[2 * M + m] = LOG2E * c2;
    C[3 * M + m] = LOG2E * -g11;
    C[4 * M + m] = LOG2E * c4;
    C[5 * M + m] = LOG2E * -g01s;
    myuni &= (g00 == rg00) & (g01 == rg01) & (g11 == rg11);
  }
  uni[t] = myuni; __syncthreads();
  for (int s = 128; s > 0; s >>= 1) {
    if (t < s) uni[t] &= uni[t + s];
    __syncthreads();
  }
  if (t == 0) {
    ((int*)C)[6 * M + 0] = uni[0];
    C[6 * M + 1] = LOG2E * -rg00;        // cb1
    C[6 * M + 2] = LOG2E * -rg11;        // cb3
    C[6 * M + 3] = LOG2E * -2.0f * rg01; // cb5
  }
}

// eval 8 comps (2 pk_fma each) + COMPLETE packed max tree over all 8
static __device__ __forceinline__ void eval_tree(
    const float* __restrict__ C0, const float* __restrict__ C2,
    const float* __restrict__ C4, int m, v2f x0p, v2f x1p,
    v2f a[CH], v2f& cm) {
#pragma unroll
  for (int j = 0; j < CH; ++j) {
    const float c0 = C0[m + j], c2 = C2[m + j], c4 = C4[m + j];
    v2f t = x0p * c2 + c0;     // v_pk_fma_f32
    a[j] = x1p * c4 + t;       // v_pk_fma_f32
  }
  const v2f t0 = PKMAX(a[0], a[1]);
  const v2f t1 = PKMAX(a[2], a[3]);
  const v2f t2 = PKMAX(a[4], a[5]);
  const v2f t3 = PKMAX(a[6], a[7]);
  cm = PKMAX(PKMAX(t0, t1), PKMAX(t2, t3));
}

// exp-phase: rescale running sum, add exp2 of all 8 elems (trans-heavy)
static __device__ __forceinline__ void exp_phase(
    const v2f a[CH], v2f cm, v2f& mx, v2f& s) {
  const v2f nm = PKMAX(mx, cm);
  const v2f dm = mx - nm;                  // <=0; first chunk -inf -> 0
  const v2f resc = {EXP2(dm.x), EXP2(dm.y)};
  v2f l0 = {0.f, 0.f}, l1 = {0.f, 0.f};
#pragma unroll
  for (int j = 0; j < CH; j += 2) {
    const v2f d0 = a[j] - nm;              // v_pk_add_f32
    const v2f d1 = a[j + 1] - nm;
    const v2f e0 = {EXP2(d0.x), EXP2(d0.y)};
    const v2f e1 = {EXP2(d1.x), EXP2(d1.y)};
    l0 += e0; l1 += e1;                    // v_pk_add_f32
  }
  s = s * resc + (l0 + l1);                // v_pk_fma_f32
  mx = nm;
}

// One block = 512 threads = 8 waves; all waves cover the SAME 128 samples
// (lane l -> samples blk*128+l and +64), wave v covers comps [v*M/8,(v+1)*M/8).
__global__ __launch_bounds__(512, 4) void gmix_kernel(
    const float* __restrict__ sample,
    const float* __restrict__ C,
    float* __restrict__ out,
    int N, int M) {
  __shared__ float Lmx[SPLIT][2][64];
  __shared__ float Lsm[SPLIT][2][64];

  const int lane = threadIdx.x & 63;
  const int wave = __builtin_amdgcn_readfirstlane((int)(threadIdx.x >> 6));
  const int nA = blockIdx.x * 128 + lane;
  const int nB = nA + 64;

  const float2 xA = (nA < N) ? ((const float2*)sample)[nA] : make_float2(0.f, 0.f);
  const float2 xB = (nB < N) ? ((const float2*)sample)[nB] : make_float2(0.f, 0.f);
  const v2f x0p = {xA.x, xB.x};   // lo = sample A, hi = sample B
  const v2f x1p = {xA.y, xB.y};

  const int flag = ((const int*)C)[6 * M + 0];
  const float cb1 = C[6 * M + 1];
  const float cb3 = C[6 * M + 2];
  const float cb5 = C[6 * M + 3];

  const int Mq = M / SPLIT;
  const int m0 = wave * Mq;                      // SGPR -> scalar loads
  const float* __restrict__ C0 = C + m0;
  const float* __restrict__ C1 = C + M + m0;
  const float* __restrict__ C2 = C + 2 * M + m0;
  const float* __restrict__ C3 = C + 3 * M + m0;
  const float* __restrict__ C4 = C + 4 * M + m0;
  const float* __restrict__ C5 = C + 5 * M + m0;

  v2f basep = {0.f, 0.f};
  float omxA, osA, omxB, osB;

  if (flag) {
    basep = cb1 * x0p * x0p + cb3 * x1p * x1p + cb5 * x0p * x1p;
    v2f mx = {-INFINITY, -INFINITY};
    v2f s  = {0.f, 0.f};
    v2f aP[CH], aQ[CH], cmP, cmQ;

    // prologue: eval chunk 0 into P
    eval_tree(C0, C2, C4, 0, x0p, x1p, aP, cmP);
    // steady state: each segment pairs an eval (full-rate) with an
    // exp-phase of the previously evaluated chunk (trans) -> mixed-pipe
#pragma unroll 1
    for (int m = CH; m + CH < Mq; m += 2 * CH) {
      eval_tree(C0, C2, C4, m, x0p, x1p, aQ, cmQ);
      exp_phase(aP, cmP, mx, s);
      eval_tree(C0, C2, C4, m + CH, x0p, x1p, aP, cmP);
      exp_phase(aQ, cmQ, mx, s);
    }
    // epilogue: last chunk eval + drain both buffers
    eval_tree(C0, C2, C4, Mq - CH, x0p, x1p, aQ, cmQ);
    exp_phase(aP, cmP, mx, s);
    exp_phase(aQ, cmQ, mx, s);

    omxA = mx.x; osA = s.x; omxB = mx.y; osB = s.y;
  } else {
    float mxA = -INFINITY, sA = 0.0f;
    float mxB = -INFINITY, sB = 0.0f;
    for (int m = 0; m < Mq; m += CHG) {
      v2f a[CHG];
#pragma unroll
      for (int j = 0; j < CHG; ++j) {
        const float c0 = C0[m + j], c1 = C1[m + j], c2 = C2[m + j];
        const float c3 = C3[m + j], c4 = C4[m + j], c5 = C5[m + j];
        v2f t0 = x0p * c1 + c2;
        t0 = x1p * c5 + t0;
        v2f t1 = x1p * c3 + c4;
        v2f r = t0 * x0p + c0;
        a[j] = t1 * x1p + r;
      }
      v2f cm01 = PKMAX(a[0], a[1]);
      v2f cm23 = PKMAX(a[2], a[3]);
      v2f cm45 = PKMAX(a[4], a[5]);
      v2f cm67 = PKMAX(a[6], a[7]);
#pragma unroll
      for (int j = 8; j < CHG; j += 4) {
        cm01 = PKMAX(cm01, a[j]);
        cm23 = PKMAX(cm23, a[j + 1]);
        cm45 = PKMAX(cm45, a[j + 2]);
        cm67 = PKMAX(cm67, a[j + 3]);
      }
      const v2f cm = PKMAX(PKMAX(cm01, cm23), PKMAX(cm45, cm67));
      const float nmA = fmaxf(mxA, cm.x);
      const float nmB = fmaxf(mxB, cm.y);
      sA *= EXP2(mxA - nmA);
      sB *= EXP2(mxB - nmB);
      const v2f nmp = {nmA, nmB};
      float lA0 = 0.f, lA1 = 0.f, lB0 = 0.f, lB1 = 0.f;
#pragma unroll
      for (int j = 0; j < CHG; j += 2) {
        const v2f d0 = a[j] - nmp;
        const v2f d1 = a[j + 1] - nmp;
        lA0 += EXP2(d0.x);
        lB0 += EXP2(d0.y);
        lA1 += EXP2(d1.x);
        lB1 += EXP2(d1.y);
      }
      sA += lA0 + lA1; mxA = nmA;
      sB += lB0 + lB1; mxB = nmB;
    }
    omxA = mxA; osA = sA; omxB = mxB; osB = sB;
  }

  // fold per-sample base into the partial max: logsumexp shifts uniformly
  Lmx[wave][0][lane] = omxA + basep.x; Lsm[wave][0][lane] = osA;
  Lmx[wave][1][lane] = omxB + basep.y; Lsm[wave][1][lane] = osB;
  __syncthreads();

  if (wave < 2) {
    const int set = wave;
    const int n = blockIdx.x * 128 + set * 64 + lane;
    if (n < N) {
      float gm = Lmx[0][set][lane];
#pragma unroll
      for (int v = 1; v < SPLIT; ++v) gm = fmaxf(gm, Lmx[v][set][lane]);
      float S = 0.f;
#pragma unroll
      for (int v = 0; v < SPLIT; ++v)
        S += Lsm[v][set][lane] * EXP2(Lmx[v][set][lane] - gm);
      out[n] = (gm + __log2f(S)) * 0.69314718055994530942f;
    }
  }
}

extern "C" void kernel_launch(void* const* d_in, const int* in_sizes, int n_in,
                              void* d_out, int out_size, void* d_ws, size_t ws_size,
                              hipStream_t stream) {
  const float* sample = (const float*)d_in[0];
  const float* mu     = (const float*)d_in[1];
  const float* A      = (const float*)d_in[2];
  const float* w      = (const float*)d_in[3];
  float* out = (float*)d_out;

  const int N = in_sizes[0] / 2;   // sample is (N,2)
  const int M = in_sizes[3];       // w is (M,1)

  float* C = (float*)d_ws;         // 6*M floats + 4-float header

  prep_kernel<<<1, 256, 0, stream>>>(mu, A, w, C, M);
  gmix_kernel<<<(N + 127) / 128, 512, 0, stream>>>(sample, C, out, N, M);
}

// Round 4
// 110.548 us; speedup vs baseline: 1.0003x; 1.0003x over previous
//
#include <hip/hip_runtime.h>
#include <math.h>

// GaussianMixture log-likelihood: ll[n] = logsumexp_m( wlog[m] - dx^T G_m dx )
// arg(n,m) = c0 + c1*x0^2 + c2*x0 + c3*x1^2 + c4*x1 + c5*x0*x1  (log2-scaled)
// R9b: R9 with compile fix (V4MAX needs both args v4f -> splat SCH_TMIN).
// R6-R8 post-mortem: runtime invariant (~50us) under every schedule
// restructure; per-comp cost 58 cyc vs ~26 issued -> v_exp_f32 (trans pipe)
// is the bottleneck, not scheduling. Fix: hot loop uses packed Schraudolph
// exp2 (full-rate only): t = a*2^23 + (K2 - nm*2^23)  [subtract folded into
// the per-chunk constant], clamp at Tmin (REQUIRED: i32 cvt saturation would
// bitcast to negative floats), v_cvt_i32_f32, bitcast. ~3 full-rate ops/exp,
// 0 trans. Rel err <= ~3% -> |d ll| <= 0.03 << 0.125 tol.
// Also 4 samples/lane (v4f): halves per-sample scalar-load/loop overhead,
// doubles per-wave ILP. Rescale + final combine + general path keep hw exp2.
// Max tree stays COMPLETE over every element (R5 NaN lesson).
// readfirstlane on wave id keeps coefficient loads scalar (R3 lesson).

#if __has_builtin(__builtin_amdgcn_exp2f)
#define EXP2(x) __builtin_amdgcn_exp2f(x)
#else
#define EXP2(x) exp2f(x)
#endif

typedef float v4f __attribute__((ext_vector_type(4)));
typedef int   i4  __attribute__((ext_vector_type(4)));

#if __has_builtin(__builtin_elementwise_max)
#define V4MAX(a, b) __builtin_elementwise_max(a, b)
#else
static __device__ inline v4f V4MAX(v4f a, v4f b) {
  v4f r; r.x = fmaxf(a.x, b.x); r.y = fmaxf(a.y, b.y);
  r.z = fmaxf(a.z, b.z); r.w = fmaxf(a.w, b.w); return r;
}
#endif

static __device__ __forceinline__ v4f exp2_hw4(v4f d) {
  v4f r; r.x = EXP2(d.x); r.y = EXP2(d.y); r.z = EXP2(d.z); r.w = EXP2(d.w);
  return r;
}

// Schraudolph exp2 constants (fp32): y = bitcast(int(x*2^23 + 127*2^23 - C)),
// C = 366393 minimizes max rel err (~+-3%).
#define SCH_K1   8388608.0f      // 2^23
#define SCH_K2   1064986823.0f   // 127*2^23 - 366393
#define SCH_TMIN 58353856.0f     // SCH_K2 - 120*2^23  (clamp: keeps cvt valid)

#define SPLIT 8
#define CH  16   // fast-path chunk
#define CHG 8    // general-path chunk

__global__ __launch_bounds__(256) void prep_kernel(
    const float* __restrict__ mu,
    const float* __restrict__ A,
    const float* __restrict__ w,
    float* __restrict__ C,   // [6][M] planes + header {flag, cb1, cb3, cb5}
    int M) {
  __shared__ float red[256];
  __shared__ int uni[256];
  const int t = threadIdx.x;

  float mx = -INFINITY;
  for (int m = t; m < M; m += 256) mx = fmaxf(mx, w[m]);
  red[t] = mx; __syncthreads();
  for (int s = 128; s > 0; s >>= 1) {
    if (t < s) red[t] = fmaxf(red[t], red[t + s]);
    __syncthreads();
  }
  const float wmax = red[0]; __syncthreads();

  float sum = 0.f;
  for (int m = t; m < M; m += 256) sum += expf(w[m] - wmax);
  red[t] = sum; __syncthreads();
  for (int s = 128; s > 0; s >>= 1) {
    if (t < s) red[t] += red[t + s];
    __syncthreads();
  }
  const float logZ = wmax + logf(red[0]);

  const float r00 = A[0], r01 = A[1], r10 = A[2], r11 = A[3];
  const float rg00 = 0.5f * (r00 * r00 + r01 * r01);
  const float rg01 = 0.5f * (r00 * r10 + r01 * r11);
  const float rg11 = 0.5f * (r10 * r10 + r11 * r11);

  const float LOG2E = 1.44269504088896340736f;
  int myuni = 1;
  for (int m = t; m < M; m += 256) {
    const float a00 = A[m * 4 + 0], a01 = A[m * 4 + 1];
    const float a10 = A[m * 4 + 2], a11 = A[m * 4 + 3];
    const float g00 = 0.5f * (a00 * a00 + a01 * a01);
    const float g01 = 0.5f * (a00 * a10 + a01 * a11);
    const float g11 = 0.5f * (a10 * a10 + a11 * a11);
    const float g01s = 2.0f * g01;
    const float det = g00 * g11 - g01 * g01;
    const float wlog = (w[m] - logZ) + 0.5f * logf(det);
    const float mu0 = mu[m * 2 + 0], mu1 = mu[m * 2 + 1];
    const float c0 = wlog - (g00 * mu0 * mu0 + g01s * mu0 * mu1 + g11 * mu1 * mu1);
    const float c2 = 2.0f * g00 * mu0 + g01s * mu1;
    const float c4 = 2.0f * g11 * mu1 + g01s * mu0;
    C[0 * M + m] = LOG2E * c0;
    C[1 * M + m] = LOG2E * -g00;
    C[2 * M + m] = LOG2E * c2;
    C[3 * M + m] = LOG2E * -g11;
    C[4 * M + m] = LOG2E * c4;
    C[5 * M + m] = LOG2E * -g01s;
    myuni &= (g00 == rg00) & (g01 == rg01) & (g11 == rg11);
  }
  uni[t] = myuni; __syncthreads();
  for (int s = 128; s > 0; s >>= 1) {
    if (t < s) uni[t] &= uni[t + s];
    __syncthreads();
  }
  if (t == 0) {
    ((int*)C)[6 * M + 0] = uni[0];
    C[6 * M + 1] = LOG2E * -rg00;        // cb1
    C[6 * M + 2] = LOG2E * -rg11;        // cb3
    C[6 * M + 3] = LOG2E * -2.0f * rg01; // cb5
  }
}

// One block = 512 threads = 8 waves; all waves cover the SAME 256 samples
// (lane l -> samples blk*256 + l + {0,64,128,192}), wave v covers comps
// [v*M/8,(v+1)*M/8).
__global__ __launch_bounds__(512, 4) void gmix_kernel(
    const float* __restrict__ sample,
    const float* __restrict__ C,
    float* __restrict__ out,
    int N, int M) {
  __shared__ float Lmx[SPLIT][4][64];
  __shared__ float Lsm[SPLIT][4][64];

  const int lane = threadIdx.x & 63;
  const int wave = __builtin_amdgcn_readfirstlane((int)(threadIdx.x >> 6));
  const int n0 = blockIdx.x * 256 + lane;

  float2 xs0 = (n0       < N) ? ((const float2*)sample)[n0      ] : make_float2(0.f, 0.f);
  float2 xs1 = (n0 + 64  < N) ? ((const float2*)sample)[n0 + 64 ] : make_float2(0.f, 0.f);
  float2 xs2 = (n0 + 128 < N) ? ((const float2*)sample)[n0 + 128] : make_float2(0.f, 0.f);
  float2 xs3 = (n0 + 192 < N) ? ((const float2*)sample)[n0 + 192] : make_float2(0.f, 0.f);
  const v4f x0q = {xs0.x, xs1.x, xs2.x, xs3.x};
  const v4f x1q = {xs0.y, xs1.y, xs2.y, xs3.y};

  const int flag = ((const int*)C)[6 * M + 0];
  const float cb1 = C[6 * M + 1];
  const float cb3 = C[6 * M + 2];
  const float cb5 = C[6 * M + 3];

  const int Mq = M / SPLIT;
  const int m0 = wave * Mq;                      // SGPR -> scalar loads
  const float* __restrict__ C0 = C + m0;
  const float* __restrict__ C1 = C + M + m0;
  const float* __restrict__ C2 = C + 2 * M + m0;
  const float* __restrict__ C3 = C + 3 * M + m0;
  const float* __restrict__ C4 = C + 4 * M + m0;
  const float* __restrict__ C5 = C + 5 * M + m0;

  v4f base4 = {0.f, 0.f, 0.f, 0.f};
  v4f mx = {-INFINITY, -INFINITY, -INFINITY, -INFINITY};
  v4f s  = {0.f, 0.f, 0.f, 0.f};

  const v4f tminv = {SCH_TMIN, SCH_TMIN, SCH_TMIN, SCH_TMIN};

  if (flag) {
    base4 = cb1 * x0q * x0q + cb3 * x1q * x1q + cb5 * x0q * x1q;
    for (int m = 0; m < Mq; m += CH) {
      v4f a[CH];
#pragma unroll
      for (int j = 0; j < CH; ++j) {
        const float c0 = C0[m + j], c2 = C2[m + j], c4 = C4[m + j];
        v4f t = x0q * c2 + c0;     // 2x v_pk_fma_f32
        a[j] = x1q * c4 + t;       // 2x v_pk_fma_f32
      }
      // COMPLETE packed max tree over all CH elements (R5 NaN lesson)
      v4f t0 = V4MAX(a[0], a[1]);
      v4f t1 = V4MAX(a[2], a[3]);
      v4f t2 = V4MAX(a[4], a[5]);
      v4f t3 = V4MAX(a[6], a[7]);
#pragma unroll
      for (int j = 8; j < CH; j += 4) {
        t0 = V4MAX(t0, a[j]);
        t1 = V4MAX(t1, a[j + 1]);
        t2 = V4MAX(t2, a[j + 2]);
        t3 = V4MAX(t3, a[j + 3]);
      }
      const v4f cm = V4MAX(V4MAX(t0, t1), V4MAX(t2, t3));
      const v4f nm = V4MAX(mx, cm);
      const v4f resc = exp2_hw4(mx - nm);   // rare: 4 hw exp2 per 16 comps
      // Schraudolph: fold (a - nm) into the per-chunk constant
      const v4f knm = SCH_K2 - nm * SCH_K1;
      v4f l0 = {0.f, 0.f, 0.f, 0.f}, l1 = {0.f, 0.f, 0.f, 0.f};
#pragma unroll
      for (int j = 0; j < CH; j += 2) {
        v4f u0 = a[j]     * SCH_K1 + knm;   // v_pk_fma_f32
        v4f u1 = a[j + 1] * SCH_K1 + knm;
        u0 = V4MAX(u0, tminv);              // clamp: cvt must stay in range
        u1 = V4MAX(u1, tminv);
        const i4 iv0 = __builtin_convertvector(u0, i4);  // v_cvt_i32_f32 x4
        const i4 iv1 = __builtin_convertvector(u1, i4);
        l0 += __builtin_bit_cast(v4f, iv0); // int bits ARE the fp32 exp2
        l1 += __builtin_bit_cast(v4f, iv1);
      }
      s = s * resc + (l0 + l1);             // v_pk_fma_f32
      mx = nm;
    }
  } else {
    for (int m = 0; m < Mq; m += CHG) {
      v4f a[CHG];
#pragma unroll
      for (int j = 0; j < CHG; ++j) {
        const float c0 = C0[m + j], c1 = C1[m + j], c2 = C2[m + j];
        const float c3 = C3[m + j], c4 = C4[m + j], c5 = C5[m + j];
        v4f u = x0q * c1 + c2;
        u = x1q * c5 + u;
        v4f v = x1q * c3 + c4;
        v4f r = u * x0q + c0;
        a[j] = v * x1q + r;
      }
      v4f t0 = V4MAX(a[0], a[1]);
      v4f t1 = V4MAX(a[2], a[3]);
      v4f t2 = V4MAX(a[4], a[5]);
      v4f t3 = V4MAX(a[6], a[7]);
      const v4f cm = V4MAX(V4MAX(t0, t1), V4MAX(t2, t3));
      const v4f nm = V4MAX(mx, cm);
      const v4f resc = exp2_hw4(mx - nm);
      v4f l0 = {0.f, 0.f, 0.f, 0.f}, l1 = {0.f, 0.f, 0.f, 0.f};
#pragma unroll
      for (int j = 0; j < CHG; j += 2) {
        l0 += exp2_hw4(a[j] - nm);
        l1 += exp2_hw4(a[j + 1] - nm);
      }
      s = s * resc + (l0 + l1);
      mx = nm;
    }
  }

  // fold per-sample base into the partial max: logsumexp shifts uniformly
#pragma unroll
  for (int k = 0; k < 4; ++k) {
    Lmx[wave][k][lane] = mx[k] + base4[k];
    Lsm[wave][k][lane] = s[k];
  }
  __syncthreads();

  if (wave < 4) {
    const int set = wave;
    const int n = blockIdx.x * 256 + set * 64 + lane;
    if (n < N) {
      float gm = Lmx[0][set][lane];
#pragma unroll
      for (int v = 1; v < SPLIT; ++v) gm = fmaxf(gm, Lmx[v][set][lane]);
      float S = 0.f;
#pragma unroll
      for (int v = 0; v < SPLIT; ++v)
        S += Lsm[v][set][lane] * EXP2(Lmx[v][set][lane] - gm);
      out[n] = (gm + __log2f(S)) * 0.69314718055994530942f;
    }
  }
}

extern "C" void kernel_launch(void* const* d_in, const int* in_sizes, int n_in,
                              void* d_out, int out_size, void* d_ws, size_t ws_size,
                              hipStream_t stream) {
  const float* sample = (const float*)d_in[0];
  const float* mu     = (const float*)d_in[1];
  const float* A      = (const float*)d_in[2];
  const float* w      = (const float*)d_in[3];
  float* out = (float*)d_out;

  const int N = in_sizes[0] / 2;   // sample is (N,2)
  const int M = in_sizes[3];       // w is (M,1)

  float* C = (float*)d_ws;         // 6*M floats + 4-float header

  prep_kernel<<<1, 256, 0, stream>>>(mu, A, w, C, M);
  gmix_kernel<<<(N + 255) / 256, 512, 0, stream>>>(sample, C, out, N, M);
}